// Round 4
// baseline (107.400 us; speedup 1.0000x reference)
//
#include <hip/hip_runtime.h>
#include <math.h>

// Problem constants (from reference setup_inputs)
namespace {
constexpr int B = 128;
constexpr int T = 2048;
constexpr int D = 128;
constexpr int Q = D / 4;             // 32 float4 per (b,t) row
constexpr int P = 64;
constexpr int TOUT = T + P;          // 2112
constexpr int NC = 32;               // chunks along T (reverted: best measured)
constexpr int L = T / NC;            // 64 per chunk
constexpr int CPB = 4;               // chunks per block (j dimension)
constexpr float ALPHA = 0.94f;
constexpr float OMA = (float)(1.0 - 0.94);   // 1-alpha
constexpr float UCLIP = 1e-6f;
constexpr float SQRT2 = 1.41421356237309515f;
constexpr float INV_SQRT2 = 0.70710678118654752f;
constexpr float RMAX = 0.999998f;    // 1 - 2*UCLIP
}

// ---------------------------------------------------------------------------
// Fast erfinv (M. Giles). Central branch covers |x|<~0.9966; tail branch is
// rare for ~normal data (skipped via execz when no lane takes it).
// ---------------------------------------------------------------------------
__device__ __forceinline__ float fast_erfinv(float x) {
    float w = -__logf(fmaf(-x, x, 1.0f));     // -log(1-x^2), single rounding
    float p;
    if (w < 5.0f) {
        w -= 2.5f;
        p = 2.81022636e-08f;
        p = fmaf(p, w, 3.43273939e-07f);
        p = fmaf(p, w, -3.5233877e-06f);
        p = fmaf(p, w, -4.39150654e-06f);
        p = fmaf(p, w, 0.00021858087f);
        p = fmaf(p, w, -0.00125372503f);
        p = fmaf(p, w, -0.00417768164f);
        p = fmaf(p, w, 0.246640727f);
        p = fmaf(p, w, 1.50140941f);
    } else {
        w = sqrtf(w) - 3.0f;
        p = -0.000200214257f;
        p = fmaf(p, w, 0.000100950558f);
        p = fmaf(p, w, 0.00134934322f);
        p = fmaf(p, w, -0.00367342844f);
        p = fmaf(p, w, 0.00573950773f);
        p = fmaf(p, w, -0.0076224613f);
        p = fmaf(p, w, 0.00943887047f);
        p = fmaf(p, w, 1.00167406f);
        p = fmaf(p, w, 2.83297682f);
    }
    return p * x;
}

// y = x - mu, v = scale^2 (clamped). r = 2F(t)-1 with t = y/sqrt(v), df=4:
//   r = y*(6v+y^2) * rsqrt((4v+y^2)^3)      (v^{3/2} cancels; no divide)
// then z = sqrt(2)*erfinv(clip(r)).
__device__ __forceinline__ float t_to_z(float y, float v) {
    float y2 = y * y;
    float a6 = fmaf(v, 6.0f, y2);
    float a4 = fmaf(v, 4.0f, y2);
    float m  = rsqrtf(a4);
    float m3 = m * m * m;
    float r  = y * a6 * m3;                        // in [-1, 1]
    r = fminf(fmaxf(r, -RMAX), RMAX);              // == clip(u,1e-6,1-1e-6)
    return SQRT2 * fast_erfinv(r);
}

// ---------------------------------------------------------------------------
// Kernel A: per (b, chunk-group) — each thread owns a d-quad (float4) of one
// chunk: partial sum of x + chunk-local EWMA tails of x and x^2 with zero
// carry-in (chunk 0 uses true init).
// Thread map: q = t&31 (d-quad), j = t>>5 (chunk within group).
// ---------------------------------------------------------------------------
__global__ __launch_bounds__(128, 8) void kA(const float4* __restrict__ x4,
                                             float4* __restrict__ Spart,
                                             float4* __restrict__ l1e,
                                             float4* __restrict__ l2e) {
    const int t = threadIdx.x;
    const int q = t & (Q - 1);
    const int j = t >> 5;
    const int c = blockIdx.x * CPB + j;
    const int b = blockIdx.y;

    const float4* xp = x4 + ((size_t)b * T + (size_t)c * L) * Q + q;

    float sm[4], l1[4], l2[4];
    {
        float4 v = xp[0];
        float xa[4] = {v.x, v.y, v.z, v.w};
        #pragma unroll
        for (int i = 0; i < 4; ++i) {
            sm[i] = xa[i];
            float g2 = xa[i] * xa[i];
            if (c == 0) { l1[i] = xa[i];       l2[i] = g2; }
            else        { l1[i] = OMA * xa[i]; l2[i] = OMA * g2; }
        }
    }
    for (int k = 1; k < L; ++k) {
        float4 v = xp[(size_t)k * Q];
        float xa[4] = {v.x, v.y, v.z, v.w};
        #pragma unroll
        for (int i = 0; i < 4; ++i) {
            sm[i] += xa[i];
            l1[i] = fmaf(ALPHA, l1[i], OMA * xa[i]);
            l2[i] = fmaf(ALPHA, l2[i], OMA * (xa[i] * xa[i]));
        }
    }
    const size_t o = ((size_t)b * NC + c) * Q + q;
    Spart[o] = make_float4(sm[0], sm[1], sm[2], sm[3]);
    l1e[o]   = make_float4(l1[0], l1[1], l1[2], l1[3]);
    l2e[o]   = make_float4(l2[0], l2[1], l2[2], l2[3]);
}

// ---------------------------------------------------------------------------
// Kernel B: per (b,d) — stitch chunk carries exactly:
//   E_end[c] = l_end[c] + alpha^L * E_end[c-1]
// Pass 2 rewrites the combined carry crw = carry2 - 2*mu*carry1 into carry1.
// NOTE: carry1 aliases Spart, carry2 aliases l1e (same-thread load-before-
// store at each index) — so NO __restrict__ here.
// ---------------------------------------------------------------------------
__global__ __launch_bounds__(256) void kB(const float* Spart,
                                          const float* l1e,
                                          const float* l2e,
                                          float* carry1,
                                          float* carry2,
                                          float* __restrict__ loc,
                                          float* __restrict__ scf) {
    const int tid = blockIdx.x * blockDim.x + threadIdx.x;   // b*D + d
    if (tid >= B * D) return;
    const int b = tid / D;
    const int d = tid % D;

    const float alphaL = (float)pow((double)ALPHA, (double)L);  // constant-folded

    float sum = 0.0f, e1 = 0.0f, e2 = 0.0f;
    for (int c = 0; c < NC; ++c) {
        const size_t o = ((size_t)b * NC + c) * D + d;
        float sp = Spart[o];
        float t1 = l1e[o];
        float t2 = l2e[o];
        carry1[o] = e1;
        carry2[o] = e2;
        sum += sp;
        e1 = t1 + alphaL * e1;
        e2 = t2 + alphaL * e2;
    }

    const float mu = sum * (1.0f / (float)T);
    loc[tid] = mu;
    float ew = fmaxf(fmaf(mu, mu, fmaf(-2.0f * mu, e1, e2)), 0.0f);
    scf[tid] = fmaxf(sqrtf(0.5f * ew), 1e-5f);

    // fold carries: crw = carry2 - 2*mu*carry1 (stored into carry1)
    for (int c = 0; c < NC; ++c) {
        const size_t o = ((size_t)b * NC + c) * D + d;
        float c1 = carry1[o];
        float c2 = carry2[o];
        carry1[o] = fmaf(-2.0f * mu, c1, c2);
    }
}

// ---------------------------------------------------------------------------
// Kernel C: per (b, chunk-group), float4 per thread — single fused EWMA scan
// with the carry folded into the initial state:
//   s_k = alpha*s_{k-1} + (1-alpha)*x*(x-2mu),  s_0 = lw_0 + alpha*crw
//   v = max(0.5*s + 0.5*mu^2, 1e-10) = scale^2 (eps clamp folded)
// Block mapping is REVERSED vs kA so the x re-read starts from the
// freshest (least-LRU-evicted) lines in LLC.
// ---------------------------------------------------------------------------
__global__ __launch_bounds__(128, 8) void kC(const float4* __restrict__ x4,
                                             const float4* __restrict__ crwb,
                                             const float4* __restrict__ locg,
                                             float4* __restrict__ out4) {
    const int t = threadIdx.x;
    const int q = t & (Q - 1);
    const int j = t >> 5;
    const int b  = (B - 1) - blockIdx.y;              // reversed
    const int cg = (NC / CPB - 1) - blockIdx.x;       // reversed
    const int c  = cg * CPB + j;

    const size_t co = ((size_t)b * NC + c) * Q + q;
    const float4 cv = crwb[co];
    const float4 mv = locg[(size_t)b * Q + q];
    const float crw[4] = {cv.x, cv.y, cv.z, cv.w};
    const float mu[4]  = {mv.x, mv.y, mv.z, mv.w};
    float twomu[4], mu2h[4];
    #pragma unroll
    for (int i = 0; i < 4; ++i) {
        twomu[i] = 2.0f * mu[i];
        mu2h[i]  = 0.5f * mu[i] * mu[i];
    }

    const float4* xp = x4   + ((size_t)b * T    + (size_t)c * L) * Q + q;
    float4*       op = out4 + ((size_t)b * TOUT + (size_t)c * L) * Q + q;

    float s[4];
    {
        float4 v = xp[0];
        float xa[4] = {v.x, v.y, v.z, v.w};
        float r_[4];
        #pragma unroll
        for (int i = 0; i < 4; ++i) {
            float g = xa[i] * (xa[i] - twomu[i]);
            float base = (c == 0) ? g : OMA * g;
            s[i] = fmaf(ALPHA, crw[i], base);
            float vv = fmaxf(fmaf(0.5f, s[i], mu2h[i]), 1e-10f);
            r_[i] = t_to_z(xa[i] - mu[i], vv);
        }
        op[0] = make_float4(r_[0], r_[1], r_[2], r_[3]);
    }
    for (int k = 1; k < L; ++k) {
        float4 v = xp[(size_t)k * Q];
        float xa[4] = {v.x, v.y, v.z, v.w};
        float r_[4];
        #pragma unroll
        for (int i = 0; i < 4; ++i) {
            float g = xa[i] * (xa[i] - twomu[i]);
            s[i] = fmaf(ALPHA, s[i], OMA * g);
            float vv = fmaxf(fmaf(0.5f, s[i], mu2h[i]), 1e-10f);
            r_[i] = t_to_z(xa[i] - mu[i], vv);
        }
        op[(size_t)k * Q] = make_float4(r_[0], r_[1], r_[2], r_[3]);
    }
}

// ---------------------------------------------------------------------------
// Kernel D: forecasts — u = clip(ndtr(z)), student-t(4) ppf closed form.
// ---------------------------------------------------------------------------
__global__ __launch_bounds__(256) void kD(const float* __restrict__ zf,
                                          const float* __restrict__ loc,
                                          const float* __restrict__ scf,
                                          float* __restrict__ out) {
    const int idx = blockIdx.x * blockDim.x + threadIdx.x;
    if (idx >= B * P * D) return;
    const int d  = idx % D;
    const int bp = idx / D;
    const int p  = bp % P;
    const int b  = bp / P;

    float zv = zf[idx];
    float u = 0.5f * erfcf(-zv * INV_SQRT2);            // ndtr
    u = fminf(fmaxf(u, UCLIP), 1.0f - UCLIP);

    float a = 4.0f * u * (1.0f - u);
    a = fminf(fmaxf(a, UCLIP), 1.0f);
    float sa = sqrtf(a);
    float inner = cosf(acosf(sa) * (1.0f / 3.0f)) / sa - 1.0f;
    float qv = 2.0f * sqrtf(fmaxf(inner, 0.0f));

    float sgn = (u > 0.5f) ? 1.0f : ((u < 0.5f) ? -1.0f : 0.0f);
    float val = sgn * qv * scf[b * D + d] + loc[b * D + d];

    out[((size_t)b * TOUT + T + p) * D + d] = val;
}

// ---------------------------------------------------------------------------
extern "C" void kernel_launch(void* const* d_in, const int* in_sizes, int n_in,
                              void* d_out, int out_size, void* d_ws, size_t ws_size,
                              hipStream_t stream) {
    const float* x  = (const float*)d_in[0];   // (B,T,D)
    const float* zf = (const float*)d_in[1];   // (B,P,D)
    float* out = (float*)d_out;                // (B,T+P,D)

    float* ws = (float*)d_ws;
    const size_t NCH = (size_t)B * NC * D;     // 524288
    float* Spart  = ws;                        // reused as carry1 / crw
    float* l1e    = Spart + NCH;               // reused as carry2
    float* l2e    = l1e + NCH;
    float* loc    = l2e + NCH;                 // B*D
    float* scf    = loc + (size_t)B * D;       // B*D
    float* carry1 = Spart;                     // alias (see kB)
    float* carry2 = l1e;                       // alias (see kB)

    kA<<<dim3(NC / CPB, B), 128, 0, stream>>>((const float4*)x, (float4*)Spart,
                                              (float4*)l1e, (float4*)l2e);
    kB<<<(B * D + 255) / 256, 256, 0, stream>>>(Spart, l1e, l2e, carry1, carry2, loc, scf);
    kC<<<dim3(NC / CPB, B), 128, 0, stream>>>((const float4*)x, (const float4*)carry1,
                                              (const float4*)loc, (float4*)out);
    kD<<<(B * P * D + 255) / 256, 256, 0, stream>>>(zf, loc, scf, out);
}

// Round 5
// 87.568 us; speedup vs baseline: 1.2265x; 1.2265x over previous
//
#include <hip/hip_runtime.h>
#include <math.h>

// Problem constants (from reference setup_inputs)
namespace {
constexpr int B = 128;
constexpr int T = 2048;
constexpr int D = 128;
constexpr int P = 64;
constexpr int TOUT = T + P;          // 2112
constexpr int NC = 32;               // chunks along T (best measured: R2)
constexpr int L = T / NC;            // 64 per chunk
constexpr float ALPHA = 0.94f;
constexpr float OMA = (float)(1.0 - 0.94);   // 1-alpha
constexpr float UCLIP = 1e-6f;
constexpr float SQRT2 = 1.41421356237309515f;
constexpr float INV_SQRT2 = 0.70710678118654752f;
constexpr float RMAX = 0.999998f;    // 1 - 2*UCLIP
}

// ---------------------------------------------------------------------------
// Fast erfinv (M. Giles). Central branch covers |x|<~0.9966; tail branch is
// rare for ~normal data (skipped via execz when no lane takes it).
// ---------------------------------------------------------------------------
__device__ __forceinline__ float fast_erfinv(float x) {
    float w = -__logf(fmaf(-x, x, 1.0f));     // -log(1-x^2)
    float p;
    if (w < 5.0f) {
        w -= 2.5f;
        p = 2.81022636e-08f;
        p = fmaf(p, w, 3.43273939e-07f);
        p = fmaf(p, w, -3.5233877e-06f);
        p = fmaf(p, w, -4.39150654e-06f);
        p = fmaf(p, w, 0.00021858087f);
        p = fmaf(p, w, -0.00125372503f);
        p = fmaf(p, w, -0.00417768164f);
        p = fmaf(p, w, 0.246640727f);
        p = fmaf(p, w, 1.50140941f);
    } else {
        w = sqrtf(w) - 3.0f;
        p = -0.000200214257f;
        p = fmaf(p, w, 0.000100950558f);
        p = fmaf(p, w, 0.00134934322f);
        p = fmaf(p, w, -0.00367342844f);
        p = fmaf(p, w, 0.00573950773f);
        p = fmaf(p, w, -0.0076224613f);
        p = fmaf(p, w, 0.00943887047f);
        p = fmaf(p, w, 1.00167406f);
        p = fmaf(p, w, 2.83297682f);
    }
    return p * x;
}

// y = x - mu, v = scale^2 (clamped). r = 2F(t)-1 with t = y/sqrt(v), df=4:
//   r = y*(6v+y^2) * rsqrt((4v+y^2)^3)      (v^{3/2} cancels; no divide)
// then z = sqrt(2)*erfinv(clip(r)).
__device__ __forceinline__ float t_to_z(float y, float v) {
    float y2 = y * y;
    float a6 = fmaf(v, 6.0f, y2);
    float a4 = fmaf(v, 4.0f, y2);
    float m  = rsqrtf(a4);
    float m3 = m * m * m;
    float r  = y * a6 * m3;                        // in [-1, 1]
    r = fminf(fmaxf(r, -RMAX), RMAX);              // == clip(u,1e-6,1-1e-6)
    return SQRT2 * fast_erfinv(r);
}

// ---------------------------------------------------------------------------
// Kernel A: per (b, chunk) — partial sum of x (for the mean) + chunk-local
// EWMA tails of x and x^2 with zero carry-in (chunk 0 uses true init).
// (Exact R2 structure — best measured.)
// ---------------------------------------------------------------------------
__global__ __launch_bounds__(128) void kA(const float* __restrict__ x,
                                          float* __restrict__ Spart,
                                          float* __restrict__ l1e,
                                          float* __restrict__ l2e) {
    const int c = blockIdx.x;      // chunk
    const int b = blockIdx.y;      // batch
    const int d = threadIdx.x;     // feature

    const float* xp = x + ((size_t)b * T + (size_t)c * L) * D + d;

    float x0 = xp[0];
    float sum = x0;
    float l1, l2;
    if (c == 0) { l1 = x0;        l2 = x0 * x0; }
    else        { l1 = OMA * x0;  l2 = OMA * (x0 * x0); }

    for (int k = 1; k < L; ++k) {
        float xv = xp[(size_t)k * D];
        sum += xv;
        l1 = fmaf(ALPHA, l1, OMA * xv);
        l2 = fmaf(ALPHA, l2, OMA * (xv * xv));
    }

    const size_t o = ((size_t)b * NC + c) * D + d;
    Spart[o] = sum;
    l1e[o]   = l1;
    l2e[o]   = l2;
}

// ---------------------------------------------------------------------------
// Kernel B: per (b,d) — stitch chunk carries exactly:
//   E_end[c] = l_end[c] + alpha^L * E_end[c-1]
// Pass 2 rewrites the combined carry crw = carry2 - 2*mu*carry1 into carry1.
// NOTE: carry1 aliases Spart, carry2 aliases l1e (same-thread load-before-
// store at each index) — so NO __restrict__ here.
// ---------------------------------------------------------------------------
__global__ __launch_bounds__(256) void kB(const float* Spart,
                                          const float* l1e,
                                          const float* l2e,
                                          float* carry1,
                                          float* carry2,
                                          float* __restrict__ loc,
                                          float* __restrict__ scf) {
    const int tid = blockIdx.x * blockDim.x + threadIdx.x;   // b*D + d
    if (tid >= B * D) return;
    const int b = tid / D;
    const int d = tid % D;

    const float alphaL = (float)pow((double)ALPHA, (double)L);  // folded

    float sum = 0.0f, e1 = 0.0f, e2 = 0.0f;
    for (int c = 0; c < NC; ++c) {
        const size_t o = ((size_t)b * NC + c) * D + d;
        float sp = Spart[o];
        float t1 = l1e[o];
        float t2 = l2e[o];
        carry1[o] = e1;
        carry2[o] = e2;
        sum += sp;
        e1 = t1 + alphaL * e1;
        e2 = t2 + alphaL * e2;
    }

    const float mu = sum * (1.0f / (float)T);
    loc[tid] = mu;
    float ew = fmaxf(fmaf(mu, mu, fmaf(-2.0f * mu, e1, e2)), 0.0f);
    scf[tid] = fmaxf(sqrtf(0.5f * ew), 1e-5f);

    // fold carries: crw = carry2 - 2*mu*carry1 (stored into carry1)
    for (int c = 0; c < NC; ++c) {
        const size_t o = ((size_t)b * NC + c) * D + d;
        float c1 = carry1[o];
        float c2 = carry2[o];
        carry1[o] = fmaf(-2.0f * mu, c1, c2);
    }
}

// ---------------------------------------------------------------------------
// Kernel C: per (b, chunk) — single fused EWMA scan with the carry folded
// into the initial state:
//   s_k = alpha*s_{k-1} + (1-alpha)*x*(x-2mu),  s_0 = base_0 + alpha*crw
//   v = max(0.5*s + 0.5*mu^2, 1e-10) = scale^2 (eps clamp folded)
// Output stores are NON-TEMPORAL so the 138 MB of out doesn't evict x from
// the 256 MB LLC (keeps kC's x re-reads LLC-resident).
// ---------------------------------------------------------------------------
__global__ __launch_bounds__(128) void kC(const float* __restrict__ x,
                                          const float* __restrict__ crwb,
                                          const float* __restrict__ locg,
                                          float* __restrict__ out) {
    const int c = blockIdx.x;
    const int b = blockIdx.y;
    const int d = threadIdx.x;

    const size_t co = ((size_t)b * NC + c) * D + d;
    const float crw   = crwb[co];
    const float mu    = locg[b * D + d];
    const float twomu = 2.0f * mu;
    const float mu2h  = 0.5f * mu * mu;

    const float* xp = x   + ((size_t)b * T    + (size_t)c * L) * D + d;
    float*       op = out + ((size_t)b * TOUT + (size_t)c * L) * D + d;

    // k = 0
    float xv = xp[0];
    float g  = xv * (xv - twomu);
    float base = (c == 0) ? g : OMA * g;
    float s  = fmaf(ALPHA, crw, base);
    float vv = fmaxf(fmaf(0.5f, s, mu2h), 1e-10f);
    __builtin_nontemporal_store(t_to_z(xv - mu, vv), &op[0]);

    for (int k = 1; k < L; ++k) {
        xv = xp[(size_t)k * D];
        g  = xv * (xv - twomu);
        s  = fmaf(ALPHA, s, OMA * g);
        vv = fmaxf(fmaf(0.5f, s, mu2h), 1e-10f);
        __builtin_nontemporal_store(t_to_z(xv - mu, vv), &op[(size_t)k * D]);
    }
}

// ---------------------------------------------------------------------------
// Kernel D: forecasts — u = clip(ndtr(z)), student-t(4) ppf closed form.
// ---------------------------------------------------------------------------
__global__ __launch_bounds__(256) void kD(const float* __restrict__ zf,
                                          const float* __restrict__ loc,
                                          const float* __restrict__ scf,
                                          float* __restrict__ out) {
    const int idx = blockIdx.x * blockDim.x + threadIdx.x;
    if (idx >= B * P * D) return;
    const int d  = idx % D;
    const int bp = idx / D;
    const int p  = bp % P;
    const int b  = bp / P;

    float zv = zf[idx];
    float u = 0.5f * erfcf(-zv * INV_SQRT2);            // ndtr
    u = fminf(fmaxf(u, UCLIP), 1.0f - UCLIP);

    float a = 4.0f * u * (1.0f - u);
    a = fminf(fmaxf(a, UCLIP), 1.0f);
    float sa = sqrtf(a);
    float inner = cosf(acosf(sa) * (1.0f / 3.0f)) / sa - 1.0f;
    float qv = 2.0f * sqrtf(fmaxf(inner, 0.0f));

    float sgn = (u > 0.5f) ? 1.0f : ((u < 0.5f) ? -1.0f : 0.0f);
    float val = sgn * qv * scf[b * D + d] + loc[b * D + d];

    __builtin_nontemporal_store(val, &out[((size_t)b * TOUT + T + p) * D + d]);
}

// ---------------------------------------------------------------------------
extern "C" void kernel_launch(void* const* d_in, const int* in_sizes, int n_in,
                              void* d_out, int out_size, void* d_ws, size_t ws_size,
                              hipStream_t stream) {
    const float* x  = (const float*)d_in[0];   // (B,T,D)
    const float* zf = (const float*)d_in[1];   // (B,P,D)
    float* out = (float*)d_out;                // (B,T+P,D)

    float* ws = (float*)d_ws;
    const size_t NCH = (size_t)B * NC * D;     // 524288
    float* Spart  = ws;                        // reused as carry1 / crw
    float* l1e    = Spart + NCH;               // reused as carry2
    float* l2e    = l1e + NCH;
    float* loc    = l2e + NCH;                 // B*D
    float* scf    = loc + (size_t)B * D;       // B*D
    float* carry1 = Spart;                     // alias (see kB)
    float* carry2 = l1e;                       // alias (see kB)

    kA<<<dim3(NC, B), 128, 0, stream>>>(x, Spart, l1e, l2e);
    kB<<<(B * D + 255) / 256, 256, 0, stream>>>(Spart, l1e, l2e, carry1, carry2, loc, scf);
    kC<<<dim3(NC, B), 128, 0, stream>>>(x, carry1, loc, out);
    kD<<<(B * P * D + 255) / 256, 256, 0, stream>>>(zf, loc, scf, out);
}